// Round 4
// baseline (1614.524 us; speedup 1.0000x reference)
//
#include <hip/hip_runtime.h>
#include <cstdint>
#include <cstddef>

// ---------------------------------------------------------------------------
// Star-Transformer forward on MI355X. Inputs confirmed fp32 (runtime flag from
// norm_g kept for robustness). Output written in flag dtype (fp32 path live).
// ws: nodes/preLN fp32; GEMM-A-only tensors bf16 (free: MFMA rounds anyway).
// ---------------------------------------------------------------------------

typedef unsigned short u16;
typedef __attribute__((ext_vector_type(4))) float f32x4;
typedef __attribute__((ext_vector_type(8))) __bf16 bf16x8;

#define NB 8
#define SEQ 1024
#define HDIM 768
#define NHEAD 12
#define HD 64
#define DINNER 3072
#define NHID 1024
#define NOUT 5000
#define ATT_SCALE 0.125f

static __device__ __forceinline__ float b2f(u16 u) {
  union { float f; uint32_t i; } v; v.i = ((uint32_t)u) << 16; return v.f;
}
static __device__ __forceinline__ u16 f2b(float f) {
  union { float f; uint32_t i; } v; v.f = f;
  uint32_t r = v.i + 0x7fffu + ((v.i >> 16) & 1u);
  return (u16)(r >> 16);
}
static __device__ __forceinline__ float ldw(const void* p, size_t i, bool f32) {
  return f32 ? ((const float*)p)[i] : b2f(((const u16*)p)[i]);
}
static __device__ __forceinline__ uint32_t pk2(float lo, float hi) {
  return (uint32_t)f2b(lo) | ((uint32_t)f2b(hi) << 16);
}

static __device__ __forceinline__ float blk_sum(float v, float* red) {
  #pragma unroll
  for (int off = 32; off > 0; off >>= 1) v += __shfl_down(v, off, 64);
  if ((threadIdx.x & 63) == 0) red[threadIdx.x >> 6] = v;
  __syncthreads();
  float r = red[0] + red[1] + red[2] + red[3];
  __syncthreads();
  return r;
}
static __device__ __forceinline__ float blk_max(float v, float* red) {
  #pragma unroll
  for (int off = 32; off > 0; off >>= 1) v = fmaxf(v, __shfl_down(v, off, 64));
  if ((threadIdx.x & 63) == 0) red[threadIdx.x >> 6] = v;
  __syncthreads();
  float r = fmaxf(fmaxf(red[0], red[1]), fmaxf(red[2], red[3]));
  __syncthreads();
  return r;
}

// ---------------------------------------------------------------------------
// NT GEMM: C[M,N] = act(A[M,K] . W[woff + n*K + k] + bias[boff+n]).
// A: fp32 (AF32) or bf16 workspace tensor; W/bias: runtime dtype via flag;
// C: fp32 (OUTF32) or bf16. 128x128 tile, 4 waves, mfma_f32_16x16x32_bf16.
// ACT: 0=none, 1=relu.
// ---------------------------------------------------------------------------
template <int ACT, bool AF32, bool OUTF32>
__global__ __launch_bounds__(256) void gemm_nt(
    const void* __restrict__ A, const void* __restrict__ W, size_t woff,
    const void* __restrict__ bias, size_t boff, void* __restrict__ C,
    int M, int N, int K, const uint32_t* __restrict__ flagp) {
  __shared__ u16 As[128 * 32];
  __shared__ u16 Bs[128 * 32];
  const bool f32 = (*flagp == 0x3F800000u);
  const int tid  = threadIdx.x;
  const int wave = tid >> 6;
  const int lane = tid & 63;
  const int bm = blockIdx.y * 128;
  const int bn = blockIdx.x * 128;
  const int wr = wave >> 1, wc = wave & 1;
  const int r16 = lane & 15, quad = lane >> 4;
  const int srow = tid >> 2;        // 0..63
  const int scol = (tid & 3) << 3;  // 0,8,16,24 elements

  const size_t a0i = (size_t)(bm + srow) * K + scol;
  const size_t a1i = (size_t)(bm + 64 + srow) * K + scol;
  const size_t w0i = woff + (size_t)(bn + srow) * K + scol;
  const size_t w1i = woff + (size_t)(bn + 64 + srow) * K + scol;
  uint4* As0 = (uint4*)&As[srow * 32 + scol];
  uint4* As1 = (uint4*)&As[(64 + srow) * 32 + scol];
  uint4* Bs0 = (uint4*)&Bs[srow * 32 + scol];
  uint4* Bs1 = (uint4*)&Bs[(64 + srow) * 32 + scol];

  f32x4 acc[4][4] = {};

  for (int k0 = 0; k0 < K; k0 += 32) {
    uint4 a0, a1, b0, b1;
    if (AF32) {
      const float* A0 = (const float*)A + a0i + k0;
      const float* A1 = (const float*)A + a1i + k0;
      const float4 x0 = ((const float4*)A0)[0], x1 = ((const float4*)A0)[1];
      const float4 y0 = ((const float4*)A1)[0], y1 = ((const float4*)A1)[1];
      a0.x = pk2(x0.x, x0.y); a0.y = pk2(x0.z, x0.w);
      a0.z = pk2(x1.x, x1.y); a0.w = pk2(x1.z, x1.w);
      a1.x = pk2(y0.x, y0.y); a1.y = pk2(y0.z, y0.w);
      a1.z = pk2(y1.x, y1.y); a1.w = pk2(y1.z, y1.w);
    } else {
      a0 = *(const uint4*)((const u16*)A + a0i + k0);
      a1 = *(const uint4*)((const u16*)A + a1i + k0);
    }
    if (f32) {
      const float* W0 = (const float*)W + w0i + k0;
      const float* W1 = (const float*)W + w1i + k0;
      const float4 x0 = ((const float4*)W0)[0], x1 = ((const float4*)W0)[1];
      const float4 y0 = ((const float4*)W1)[0], y1 = ((const float4*)W1)[1];
      b0.x = pk2(x0.x, x0.y); b0.y = pk2(x0.z, x0.w);
      b0.z = pk2(x1.x, x1.y); b0.w = pk2(x1.z, x1.w);
      b1.x = pk2(y0.x, y0.y); b1.y = pk2(y0.z, y0.w);
      b1.z = pk2(y1.x, y1.y); b1.w = pk2(y1.z, y1.w);
    } else {
      b0 = *(const uint4*)((const u16*)W + w0i + k0);
      b1 = *(const uint4*)((const u16*)W + w1i + k0);
    }
    __syncthreads();
    *As0 = a0; *As1 = a1; *Bs0 = b0; *Bs1 = b1;
    __syncthreads();
    bf16x8 af[4], bfr[4];
    #pragma unroll
    for (int i = 0; i < 4; ++i)
      af[i] = *reinterpret_cast<const bf16x8*>(&As[(wr * 64 + i * 16 + r16) * 32 + quad * 8]);
    #pragma unroll
    for (int j = 0; j < 4; ++j)
      bfr[j] = *reinterpret_cast<const bf16x8*>(&Bs[(wc * 64 + j * 16 + r16) * 32 + quad * 8]);
    #pragma unroll
    for (int i = 0; i < 4; ++i)
      #pragma unroll
      for (int j = 0; j < 4; ++j)
        acc[i][j] = __builtin_amdgcn_mfma_f32_16x16x32_bf16(af[i], bfr[j], acc[i][j], 0, 0, 0);
  }

  #pragma unroll
  for (int j = 0; j < 4; ++j) {
    const int n = bn + wc * 64 + j * 16 + r16;
    const float bv = ldw(bias, boff + n, f32);
    #pragma unroll
    for (int i = 0; i < 4; ++i) {
      const int m0 = bm + wr * 64 + i * 16 + quad * 4;
      #pragma unroll
      for (int r = 0; r < 4; ++r) {
        float vv = acc[i][j][r] + bv;
        if (ACT == 1) vv = fmaxf(vv, 0.0f);
        if (OUTF32) ((float*)C)[(size_t)(m0 + r) * N + n] = vv;
        else        ((u16*)C)[(size_t)(m0 + r) * N + n] = f2b(vv);
      }
    }
  }
}

// x[b,l,c*256+d] = emb[src[b,l,c], d] + pos_table[l, c*256+d]  (fp32 out)
__global__ __launch_bounds__(256) void embed_k(
    const int* __restrict__ src, const void* __restrict__ emb,
    const void* __restrict__ pt, float* __restrict__ x,
    const uint32_t* __restrict__ flagp) {
  const bool f32 = (*flagp == 0x3F800000u);
  const int r = blockIdx.x;
  const int l = r & (SEQ - 1);
  const int tid = threadIdx.x;
  #pragma unroll
  for (int it = 0; it < 3; ++it) {
    const int idx = tid + it * 256;
    const int c = idx >> 8, d = idx & 255;
    const int tok = src[r * 3 + c];
    x[(size_t)r * HDIM + idx] =
        ldw(emb, (size_t)tok * 256 + d, f32) + ldw(pt, (size_t)l * HDIM + idx, f32);
  }
}

__global__ __launch_bounds__(256) void relay_mean_k(
    const float* __restrict__ x, float* __restrict__ relay) {
  const int b = blockIdx.y;
  const int h = blockIdx.x * 256 + threadIdx.x;
  float s = 0.f;
  for (int l = 0; l < SEQ; ++l) s += x[((size_t)b * SEQ + l) * HDIM + h];
  relay[b * HDIM + h] = s * (1.0f / 1024.0f);
}

// h(bf16) = LN(pre + res) * g + b    (pre, res fp32)
__global__ __launch_bounds__(256) void ln_resid_k(
    const float* __restrict__ pre, const float* __restrict__ res,
    const void* __restrict__ g, const void* __restrict__ bb, size_t goff,
    u16* __restrict__ out, const uint32_t* __restrict__ flagp) {
  __shared__ float red[4];
  const bool f32 = (*flagp == 0x3F800000u);
  const int r = blockIdx.x;
  const int tid = threadIdx.x;
  const size_t base = (size_t)r * HDIM;
  float v0 = pre[base + tid]       + res[base + tid];
  float v1 = pre[base + tid + 256] + res[base + tid + 256];
  float v2 = pre[base + tid + 512] + res[base + tid + 512];
  const float mu = blk_sum(v0 + v1 + v2, red) * (1.0f / 768.0f);
  v0 -= mu; v1 -= mu; v2 -= mu;
  const float var = blk_sum(v0 * v0 + v1 * v1 + v2 * v2, red) * (1.0f / 768.0f);
  const float rs = rsqrtf(var + 1e-5f);
  out[base + tid]       = f2b(v0 * rs * ldw(g, goff + tid, f32)       + ldw(bb, goff + tid, f32));
  out[base + tid + 256] = f2b(v1 * rs * ldw(g, goff + tid + 256, f32) + ldw(bb, goff + tid + 256, f32));
  out[base + tid + 512] = f2b(v2 * rs * ldw(g, goff + tid + 512, f32) + ldw(bb, goff + tid + 512, f32));
}

// nodes(fp32) = mask ? 0 : leaky(LN(x)*g + b)   (x fp32)
__global__ __launch_bounds__(256) void ln_leaky_mask_k(
    const float* __restrict__ x, const void* __restrict__ g,
    const void* __restrict__ bb, size_t goff, const int* __restrict__ src,
    float* __restrict__ out, const uint32_t* __restrict__ flagp) {
  __shared__ float red[4];
  const bool f32 = (*flagp == 0x3F800000u);
  const int r = blockIdx.x;
  const int tid = threadIdx.x;
  const size_t base = (size_t)r * HDIM;
  float v0 = x[base + tid], v1 = x[base + tid + 256], v2 = x[base + tid + 512];
  const float mu = blk_sum(v0 + v1 + v2, red) * (1.0f / 768.0f);
  v0 -= mu; v1 -= mu; v2 -= mu;
  const float var = blk_sum(v0 * v0 + v1 * v1 + v2 * v2, red) * (1.0f / 768.0f);
  const float rs = rsqrtf(var + 1e-5f);
  const bool masked = (src[r * 3] == 0);
  float y0 = v0 * rs * ldw(g, goff + tid, f32)       + ldw(bb, goff + tid, f32);
  float y1 = v1 * rs * ldw(g, goff + tid + 256, f32) + ldw(bb, goff + tid + 256, f32);
  float y2 = v2 * rs * ldw(g, goff + tid + 512, f32) + ldw(bb, goff + tid + 512, f32);
  y0 = y0 > 0.f ? y0 : 0.01f * y0;
  y1 = y1 > 0.f ? y1 : 0.01f * y1;
  y2 = y2 > 0.f ? y2 : 0.01f * y2;
  if (masked) { y0 = 0.f; y1 = 0.f; y2 = 0.f; }
  out[base + tid]       = y0;
  out[base + tid + 256] = y1;
  out[base + tid + 512] = y2;
}

// Ring attention: per (b,l), 4 keys {l-1, l, l+1, relay}.
__global__ __launch_bounds__(256) void ring_attn_k(
    const u16* __restrict__ q, const u16* __restrict__ k,
    const u16* __restrict__ v, const float* __restrict__ rk,
    const float* __restrict__ rv, u16* __restrict__ att) {
  __shared__ float qs[HDIM];
  __shared__ float aw[NHEAD][4];
  const int r = blockIdx.x;
  const int b = r >> 10, l = r & (SEQ - 1);
  const int tid = threadIdx.x;
  const size_t base = (size_t)r * HDIM;
  #pragma unroll
  for (int it = 0; it < 3; ++it) {
    const int idx = tid + it * 256;
    qs[idx] = b2f(q[base + idx]);
  }
  __syncthreads();
  if (tid < NHEAD * 4) {
    const int n = tid >> 2, w = tid & 3;
    float a = 0.f;
    if (w < 3) {
      const int ll = l - 1 + w;
      if (ll >= 0 && ll < SEQ) {
        const u16* kp = k + base + (size_t)(w - 1) * HDIM + n * HD;
        #pragma unroll
        for (int d = 0; d < HD; ++d) a += qs[n * HD + d] * b2f(kp[d]);
      }
    } else {
      const float* kp = rk + b * HDIM + n * HD;
      #pragma unroll
      for (int d = 0; d < HD; ++d) a += qs[n * HD + d] * kp[d];
    }
    aw[n][w] = a * ATT_SCALE;
  }
  __syncthreads();
  if (tid < NHEAD) {
    const float s0 = aw[tid][0], s1 = aw[tid][1], s2 = aw[tid][2], s3 = aw[tid][3];
    const float m = fmaxf(fmaxf(s0, s1), fmaxf(s2, s3));
    const float e0 = __expf(s0 - m), e1 = __expf(s1 - m);
    const float e2 = __expf(s2 - m), e3 = __expf(s3 - m);
    const float inv = 1.0f / (e0 + e1 + e2 + e3);
    aw[tid][0] = e0 * inv; aw[tid][1] = e1 * inv;
    aw[tid][2] = e2 * inv; aw[tid][3] = e3 * inv;
  }
  __syncthreads();
  #pragma unroll
  for (int it = 0; it < 3; ++it) {
    const int idx = tid + it * 256;
    const int n = idx >> 6;
    float acc = aw[n][3] * rv[b * HDIM + idx];
    if (l > 0)       acc += aw[n][0] * b2f(v[base - HDIM + idx]);
    acc += aw[n][1] * b2f(v[base + idx]);
    if (l < SEQ - 1) acc += aw[n][2] * b2f(v[base + HDIM + idx]);
    att[base + idx] = f2b(acc);
  }
}

// Star (relay) attention: per (b,head) block; 1025 keys = [relay; nodes].
__global__ __launch_bounds__(256) void msa2_attn_k(
    const float* __restrict__ q2, const float* __restrict__ rk2,
    const float* __restrict__ rv2, const u16* __restrict__ k2,
    const u16* __restrict__ v2, const int* __restrict__ src,
    float* __restrict__ att) {
  __shared__ float qs[HD];
  __shared__ float sc[SEQ + 1];
  __shared__ float red[4];
  const int bid = blockIdx.x;
  const int b = bid / NHEAD, n = bid % NHEAD;
  const int tid = threadIdx.x;
  const int hb = b * HDIM + n * HD;
  if (tid < HD) qs[tid] = q2[hb + tid];
  __syncthreads();
  float lmax = -1e30f;
  for (int s = tid; s <= SEQ; s += 256) {
    float sco;
    if (s == 0) {
      float a = 0.f;
      #pragma unroll
      for (int d = 0; d < HD; ++d) a += qs[d] * rk2[hb + d];
      sco = a * ATT_SCALE;
    } else {
      const int l = s - 1;
      if (src[(b * SEQ + l) * 3] == 0) {
        sco = -1e30f;
      } else {
        const u16* kp = k2 + ((size_t)b * SEQ + l) * HDIM + n * HD;
        float a = 0.f;
        #pragma unroll
        for (int d = 0; d < HD; ++d) a += qs[d] * b2f(kp[d]);
        sco = a * ATT_SCALE;
      }
    }
    sc[s] = sco;
    lmax = fmaxf(lmax, sco);
  }
  lmax = blk_max(lmax, red);
  float lsum = 0.f;
  for (int s = tid; s <= SEQ; s += 256) {
    const float e = __expf(sc[s] - lmax);
    sc[s] = e;
    lsum += e;
  }
  lsum = blk_sum(lsum, red);
  if (tid < HD) {
    const float inv = 1.0f / lsum;
    float acc = sc[0] * rv2[hb + tid];
    const u16* vp = v2 + (size_t)b * SEQ * HDIM + n * HD + tid;
    for (int l = 0; l < SEQ; ++l) acc += sc[l + 1] * b2f(vp[(size_t)l * HDIM]);
    att[hb + tid] = acc * inv;
  }
}

// Tiny NT projections from 8-row relay activations; one wave per output.
// act: 0=none, 2=leaky(0.01).
__global__ __launch_bounds__(256) void relay_proj_k(
    const float* __restrict__ A, int K, int N, int nm,
    const void* W0, const void* W1, const void* W2, size_t woff,
    const void* b0, const void* b1, const void* b2v, size_t boff,
    float* O0, float* O1, float* O2, int act,
    const uint32_t* __restrict__ flagp) {
  const bool f32 = (*flagp == 0x3F800000u);
  const int wid = blockIdx.x * 4 + (threadIdx.x >> 6);
  const int lane = threadIdx.x & 63;
  if (wid >= nm * NB * N) return;
  const int mat = wid / (NB * N);
  const int rem = wid % (NB * N);
  const int b = rem / N, n = rem % N;
  const void* W  = mat == 0 ? W0 : (mat == 1 ? W1 : W2);
  const void* bb = mat == 0 ? b0 : (mat == 1 ? b1 : b2v);
  float* O       = mat == 0 ? O0 : (mat == 1 ? O1 : O2);
  const float* a = A + (size_t)b * K;
  const size_t wbase = woff + (size_t)n * K;
  float acc = 0.f;
  for (int k = lane; k < K; k += 64) acc += a[k] * ldw(W, wbase + k, f32);
  #pragma unroll
  for (int off = 32; off > 0; off >>= 1) acc += __shfl_down(acc, off, 64);
  if (lane == 0) {
    float v = acc + ldw(bb, boff + n, f32);
    if (act == 2) v = v > 0.f ? v : 0.01f * v;
    O[(size_t)b * N + n] = v;
  }
}

// ft[b] = [relay[b] ; nodes[b, positions[b]]]
__global__ __launch_bounds__(256) void ft_k(
    const float* __restrict__ relay, const float* __restrict__ nodes,
    const int* __restrict__ positions, float* __restrict__ ft) {
  const int gid = blockIdx.x * 256 + threadIdx.x;
  const int b = gid / 1536, j = gid % 1536;
  if (j < HDIM) {
    ft[gid] = relay[b * HDIM + j];
  } else {
    const int p = positions[b];
    ft[gid] = nodes[((size_t)b * SEQ + p) * HDIM + (j - HDIM)];
  }
}

// hid[j,b,o] = relu(ft[b] . head_w1[j,o] + head_b1[j,o]); one wave per output
__global__ __launch_bounds__(256) void head1_k(
    const float* __restrict__ ft, const void* __restrict__ w,
    const void* __restrict__ bias, float* __restrict__ hid,
    const uint32_t* __restrict__ flagp) {
  const bool f32 = (*flagp == 0x3F800000u);
  const int wid = blockIdx.x * 4 + (threadIdx.x >> 6);
  const int lane = threadIdx.x & 63;
  const int j = wid >> 13;
  const int rem = wid & 8191;
  const int b = rem >> 10, o = rem & 1023;
  const float* a = ft + b * 1536;
  const size_t wbase = ((size_t)j * NHID + o) * 1536;
  float acc = 0.f;
  for (int k = lane; k < 1536; k += 64) acc += a[k] * ldw(w, wbase + k, f32);
  #pragma unroll
  for (int off = 32; off > 0; off >>= 1) acc += __shfl_down(acc, off, 64);
  if (lane == 0)
    hid[((size_t)j * NB + b) * NHID + o] = fmaxf(acc + ldw(bias, j * NHID + o, f32), 0.f);
}

// out[(b*3+j), o] = hid[j,b] . head_w2[j,o] + head_b2[j,o]   (flag dtype out)
__global__ __launch_bounds__(256) void head2_k(
    const float* __restrict__ hid, const void* __restrict__ w,
    const void* __restrict__ bias, void* __restrict__ out,
    const uint32_t* __restrict__ flagp) {
  const bool f32 = (*flagp == 0x3F800000u);
  const int wid = blockIdx.x * 4 + (threadIdx.x >> 6);
  const int lane = threadIdx.x & 63;
  const int j = wid / 40000;
  const int rem = wid % 40000;
  const int b = rem / 5000, o = rem % 5000;
  const float* a = hid + ((size_t)j * NB + b) * NHID;
  const size_t wbase = ((size_t)j * NOUT + o) * NHID;
  float acc = 0.f;
  for (int k = lane; k < NHID; k += 64) acc += a[k] * ldw(w, wbase + k, f32);
  #pragma unroll
  for (int off = 32; off > 0; off >>= 1) acc += __shfl_down(acc, off, 64);
  if (lane == 0) {
    const float v = acc + ldw(bias, j * NOUT + o, f32);
    const size_t idx = (size_t)(b * 3 + j) * NOUT + o;
    if (f32) ((float*)out)[idx] = v;
    else     ((u16*)out)[idx] = f2b(v);
  }
}

// ---------------------------------------------------------------------------
extern "C" void kernel_launch(void* const* d_in, const int* in_sizes, int n_in,
                              void* d_out, int out_size, void* d_ws, size_t ws_size,
                              hipStream_t stream) {
  (void)in_sizes; (void)n_in; (void)out_size; (void)ws_size;
  const int* src       = (const int*)d_in[0];
  const int* positions = (const int*)d_in[1];
  const void* emb   = d_in[2];
  const void* pt    = d_in[3];
  const void* norm_g = d_in[4]; const void* norm_b = d_in[5];
  const void* pw_w1 = d_in[6];  const void* pw_b1 = d_in[7];
  const void* pw_w2 = d_in[8];  const void* pw_b2 = d_in[9];
  const void* pw_g  = d_in[10]; const void* pw_bn = d_in[11];
  const void* ring_wq = d_in[12]; const void* ring_bq = d_in[13];
  const void* ring_wk = d_in[14]; const void* ring_bk = d_in[15];
  const void* ring_wv = d_in[16]; const void* ring_bv = d_in[17];
  const void* ring_wo = d_in[18]; const void* ring_bo = d_in[19];
  const void* star_wq = d_in[20]; const void* star_bq = d_in[21];
  const void* star_wk = d_in[22]; const void* star_bk = d_in[23];
  const void* star_wv = d_in[24]; const void* star_bv = d_in[25];
  const void* star_wo = d_in[26]; const void* star_bo = d_in[27];
  const void* head_w1 = d_in[28]; const void* head_b1 = d_in[29];
  const void* head_w2 = d_in[30]; const void* head_b2 = d_in[31];
  const uint32_t* flagp = (const uint32_t*)d_in[4];  // norm_g == ones

  // workspace layout (bytes)
  char* ws = (char*)d_ws;
  const size_t TOKS_F32 = (size_t)NB * SEQ * HDIM * 4;  // 25,165,824
  const size_t TOKS_B16 = (size_t)NB * SEQ * HDIM * 2;  // 12,582,912
  float* nodes = (float*)(ws);
  float* preln = (float*)(ws + TOKS_F32);
  u16* cbase   = (u16*)(ws + 2 * TOKS_F32);  // 50,331,648: inner | qkv+att | k2,v2
  u16* inner = cbase;
  u16* slotC0 = cbase;
  u16* slotC1 = cbase + 1 * (size_t)NB * SEQ * HDIM;
  u16* slotC2 = cbase + 2 * (size_t)NB * SEQ * HDIM;
  u16* slotC3 = cbase + 3 * (size_t)NB * SEQ * HDIM;
  u16* hbuf  = (u16*)(ws + 2 * TOKS_F32 + 4 * TOKS_B16);
  char* small = ws + 2 * TOKS_F32 + 5 * TOKS_B16;
  float* relay = (float*)(small);
  float* sb0 = (float*)(small + 1 * 24576);
  float* sb1 = (float*)(small + 2 * 24576);
  float* sb2 = (float*)(small + 3 * 24576);
  float* sb3 = (float*)(small + 4 * 24576);
  float* ftb = (float*)(small + 5 * 24576);
  float* hid = (float*)(small + 5 * 24576 + 49152);

  embed_k<<<NB * SEQ, 256, 0, stream>>>(src, emb, pt, nodes, flagp);
  relay_mean_k<<<dim3(3, NB), 256, 0, stream>>>(nodes, relay);

  for (int i = 0; i < 2; ++i) {
    const size_t oW1 = (size_t)i * DINNER * HDIM;  // also pw_w2 layer stride
    const size_t oB1 = (size_t)i * DINNER;
    const size_t oH  = (size_t)i * HDIM;
    const size_t oQK = (size_t)i * HDIM * HDIM;

    // PWFF: inner = relu(nodes.w1^T); preln = inner.w2^T; h = LN(preln+nodes)
    gemm_nt<1, true, false><<<dim3(DINNER / 128, 64), 256, 0, stream>>>(
        nodes, pw_w1, oW1, pw_b1, oB1, inner, NB * SEQ, DINNER, HDIM, flagp);
    gemm_nt<0, false, true><<<dim3(HDIM / 128, 64), 256, 0, stream>>>(
        inner, pw_w2, oW1, pw_b2, oH, preln, NB * SEQ, HDIM, DINNER, flagp);
    ln_resid_k<<<NB * SEQ, 256, 0, stream>>>(preln, nodes, pw_g, pw_bn, oH, hbuf, flagp);

    // ring attention: q/k/v in C0-2, att in C3, wo-out in preln
    gemm_nt<0, false, false><<<dim3(HDIM / 128, 64), 256, 0, stream>>>(
        hbuf, ring_wq, oQK, ring_bq, oH, slotC0, NB * SEQ, HDIM, HDIM, flagp);
    gemm_nt<0, false, false><<<dim3(HDIM / 128, 64), 256, 0, stream>>>(
        hbuf, ring_wk, oQK, ring_bk, oH, slotC1, NB * SEQ, HDIM, HDIM, flagp);
    gemm_nt<0, false, false><<<dim3(HDIM / 128, 64), 256, 0, stream>>>(
        hbuf, ring_wv, oQK, ring_bv, oH, slotC2, NB * SEQ, HDIM, HDIM, flagp);
    relay_proj_k<<<(2 * NB * HDIM) / 4, 256, 0, stream>>>(
        relay, HDIM, HDIM, 2, ring_wk, ring_wv, ring_wk, oQK,
        ring_bk, ring_bv, ring_bk, oH, sb0, sb1, sb2, 0, flagp);
    ring_attn_k<<<NB * SEQ, 256, 0, stream>>>(slotC0, slotC1, slotC2, sb0, sb1, slotC3);
    gemm_nt<0, false, true><<<dim3(HDIM / 128, 64), 256, 0, stream>>>(
        slotC3, ring_wo, oQK, ring_bo, oH, preln, NB * SEQ, HDIM, HDIM, flagp);
    ln_leaky_mask_k<<<NB * SEQ, 256, 0, stream>>>(preln, norm_g, norm_b, oH, src, nodes, flagp);

    // star (relay) attention: k2 -> C0, v2 -> C1
    gemm_nt<0, true, false><<<dim3(HDIM / 128, 64), 256, 0, stream>>>(
        nodes, star_wk, oQK, star_bk, oH, slotC0, NB * SEQ, HDIM, HDIM, flagp);
    gemm_nt<0, true, false><<<dim3(HDIM / 128, 64), 256, 0, stream>>>(
        nodes, star_wv, oQK, star_bv, oH, slotC1, NB * SEQ, HDIM, HDIM, flagp);
    relay_proj_k<<<(3 * NB * HDIM) / 4, 256, 0, stream>>>(
        relay, HDIM, HDIM, 3, star_wq, star_wk, star_wv, oQK,
        star_bq, star_bk, star_bv, oH, sb0, sb1, sb2, 0, flagp);
    msa2_attn_k<<<NB * NHEAD, 256, 0, stream>>>(sb0, sb1, sb2, slotC0, slotC1, src, sb3);
    relay_proj_k<<<(NB * HDIM) / 4, 256, 0, stream>>>(
        sb3, HDIM, HDIM, 1, star_wo, star_wo, star_wo, oQK,
        star_bo, star_bo, star_bo, oH, relay, sb1, sb2, 2, flagp);
  }

  ft_k<<<48, 256, 0, stream>>>(relay, nodes, positions, ftb);
  head1_k<<<(3 * NB * NHID) / 4, 256, 0, stream>>>(ftb, head_w1, head_b1, hid, flagp);
  head2_k<<<(3 * NB * NOUT) / 4, 256, 0, stream>>>(hid, head_w2, head_b2, d_out, flagp);
}

// Round 5
// 1166.018 us; speedup vs baseline: 1.3846x; 1.3846x over previous
//
#include <hip/hip_runtime.h>
#include <cstdint>
#include <cstddef>

// ---------------------------------------------------------------------------
// Star-Transformer forward on MI355X. Inputs fp32 (confirmed R3/R4), output
// fp32. All GEMMs bf16 MFMA: weights converted fp32->bf16 per layer into a
// rotating ws buffer; activations kept bf16 (plus fp32 shadows where LN
// accuracy needs it). GEMM staging: global_load_lds width 16 (m97 style).
// ws ~110.8 MB (<= 113.5 proven in R4).
// ---------------------------------------------------------------------------

typedef unsigned short u16;
typedef __attribute__((ext_vector_type(4))) float f32x4;
typedef __attribute__((ext_vector_type(8))) __bf16 bf16x8;

#define NB 8
#define SEQ 1024
#define HDIM 768
#define NHEAD 12
#define HD 64
#define DINNER 3072
#define NHID 1024
#define NOUT 5000
#define ATT_SCALE 0.125f

static __device__ __forceinline__ float b2f(u16 u) {
  union { float f; uint32_t i; } v; v.i = ((uint32_t)u) << 16; return v.f;
}
static __device__ __forceinline__ u16 f2b(float f) {
  union { float f; uint32_t i; } v; v.f = f;
  uint32_t r = v.i + 0x7fffu + ((v.i >> 16) & 1u);
  return (u16)(r >> 16);
}

// async global->LDS, 16B per lane; LDS dest = wave-uniform base + lane*16.
static __device__ __forceinline__ void gl2lds16(const void* g, void* l) {
  __builtin_amdgcn_global_load_lds(
      (__attribute__((address_space(1))) void*)(uintptr_t)g,
      (__attribute__((address_space(3))) void*)l, 16, 0, 0);
}

static __device__ __forceinline__ float blk_sum(float v, float* red) {
  #pragma unroll
  for (int off = 32; off > 0; off >>= 1) v += __shfl_down(v, off, 64);
  if ((threadIdx.x & 63) == 0) red[threadIdx.x >> 6] = v;
  __syncthreads();
  float r = red[0] + red[1] + red[2] + red[3];
  __syncthreads();
  return r;
}
static __device__ __forceinline__ float blk_max(float v, float* red) {
  #pragma unroll
  for (int off = 32; off > 0; off >>= 1) v = fmaxf(v, __shfl_down(v, off, 64));
  if ((threadIdx.x & 63) == 0) red[threadIdx.x >> 6] = v;
  __syncthreads();
  float r = fmaxf(fmaxf(red[0], red[1]), fmaxf(red[2], red[3]));
  __syncthreads();
  return r;
}

// ---------------------------------------------------------------------------
// Segmented fp32 -> bf16 converter (up to 4 tensors per dispatch).
// c1..c4 are cumulative float4 counts.
// ---------------------------------------------------------------------------
struct Cvt4 {
  const float* s0; const float* s1; const float* s2; const float* s3;
  u16* d0; u16* d1; u16* d2; u16* d3;
  int c1, c2, c3, c4;
};
__global__ __launch_bounds__(256) void cvt4_k(Cvt4 a) {
  const int i = blockIdx.x * 256 + threadIdx.x;
  if (i >= a.c4) return;
  const float* s; u16* d; int j;
  if (i < a.c1)      { s = a.s0; d = a.d0; j = i; }
  else if (i < a.c2) { s = a.s1; d = a.d1; j = i - a.c1; }
  else if (i < a.c3) { s = a.s2; d = a.d2; j = i - a.c2; }
  else               { s = a.s3; d = a.d3; j = i - a.c3; }
  const float4 v = ((const float4*)s)[j];
  ushort4 o;
  o.x = f2b(v.x); o.y = f2b(v.y); o.z = f2b(v.z); o.w = f2b(v.w);
  ((ushort4*)d)[j] = o;
}

// ---------------------------------------------------------------------------
// NT GEMM: C[M,N] = act(A[M,K] . Wz[N,K]^T + biasz[N]) for z = blockIdx.z.
// All bf16 operands, fp32 bias, bf16 out. 128x128 tile, 4 waves, 64x64/wave,
// mfma_f32_16x16x32_bf16, global_load_lds width-16 staging. ACT: 0=none 1=relu.
// ---------------------------------------------------------------------------
template <int ACT>
__global__ __launch_bounds__(256) void gemm_bt(
    const u16* __restrict__ A,
    const u16* W0, const u16* W1, const u16* W2,
    const float* b0, const float* b1, const float* b2,
    u16* C0, u16* C1, u16* C2,
    int M, int N, int K) {
  __shared__ u16 As[128 * 32];
  __shared__ u16 Bs[128 * 32];
  const int z = blockIdx.z;
  const u16* W = z == 0 ? W0 : (z == 1 ? W1 : W2);
  const float* bias = z == 0 ? b0 : (z == 1 ? b1 : b2);
  u16* C = z == 0 ? C0 : (z == 1 ? C1 : C2);

  const int tid  = threadIdx.x;
  const int wave = tid >> 6;
  const int lane = tid & 63;
  const int bm = blockIdx.y * 128;
  const int bn = blockIdx.x * 128;
  const int wrq = wave >> 1, wcq = wave & 1;
  const int r16 = lane & 15, quad = lane >> 4;
  const int srow = lane >> 2;        // 0..15
  const int scol = (lane & 3) << 3;  // 0,8,16,24 bf16 elements

  f32x4 acc[4][4] = {};

  for (int k0 = 0; k0 < K; k0 += 32) {
    __syncthreads();  // previous iteration's LDS reads complete
    #pragma unroll
    for (int t = 0; t < 2; ++t) {
      const int rowa = wave * 32 + t * 16;
      gl2lds16(A + (size_t)(bm + rowa + srow) * K + (k0 + scol), (char*)As + (rowa << 6));
      gl2lds16(W + (size_t)(bn + rowa + srow) * K + (k0 + scol), (char*)Bs + (rowa << 6));
    }
    __syncthreads();  // staging visible (vmcnt drained by barrier)
    bf16x8 af[4], bf[4];
    #pragma unroll
    for (int i = 0; i < 4; ++i)
      af[i] = *reinterpret_cast<const bf16x8*>(&As[(wrq * 64 + i * 16 + r16) * 32 + quad * 8]);
    #pragma unroll
    for (int j = 0; j < 4; ++j)
      bf[j] = *reinterpret_cast<const bf16x8*>(&Bs[(wcq * 64 + j * 16 + r16) * 32 + quad * 8]);
    #pragma unroll
    for (int i = 0; i < 4; ++i)
      #pragma unroll
      for (int j = 0; j < 4; ++j)
        acc[i][j] = __builtin_amdgcn_mfma_f32_16x16x32_bf16(af[i], bf[j], acc[i][j], 0, 0, 0);
  }

  #pragma unroll
  for (int j = 0; j < 4; ++j) {
    const int n = bn + wcq * 64 + j * 16 + r16;
    const float bv = bias[n];
    #pragma unroll
    for (int i = 0; i < 4; ++i) {
      const int m0 = bm + wrq * 64 + i * 16 + quad * 4;
      #pragma unroll
      for (int r = 0; r < 4; ++r) {
        float vv = acc[i][j][r] + bv;
        if (ACT == 1) vv = fmaxf(vv, 0.0f);
        C[(size_t)(m0 + r) * N + n] = f2b(vv);
      }
    }
  }
}

// x[b,l,.] = emb[src] + pos_table  -> fp32 nodes + bf16 shadow
__global__ __launch_bounds__(256) void embed_k(
    const int* __restrict__ src, const float* __restrict__ emb,
    const float* __restrict__ pt, float* __restrict__ x,
    u16* __restrict__ xb) {
  const int r = blockIdx.x;
  const int l = r & (SEQ - 1);
  const int tid = threadIdx.x;
  #pragma unroll
  for (int it = 0; it < 3; ++it) {
    const int idx = tid + it * 256;
    const int c = idx >> 8, d = idx & 255;
    const int tok = src[r * 3 + c];
    const float v = emb[(size_t)tok * 256 + d] + pt[(size_t)l * HDIM + idx];
    x[(size_t)r * HDIM + idx] = v;
    xb[(size_t)r * HDIM + idx] = f2b(v);
  }
}

// two-stage relay mean
__global__ __launch_bounds__(256) void relay_mean1_k(
    const float* __restrict__ x, float* __restrict__ part) {
  const int cg = blockIdx.x, seg = blockIdx.y, b = blockIdx.z;
  const int h = cg * 256 + threadIdx.x;
  float s = 0.f;
  const int l0 = seg * 64;
  for (int l = l0; l < l0 + 64; ++l) s += x[((size_t)b * SEQ + l) * HDIM + h];
  part[((size_t)b * 16 + seg) * HDIM + h] = s;
}
__global__ __launch_bounds__(256) void relay_mean2_k(
    const float* __restrict__ part, float* __restrict__ relay) {
  const int b = blockIdx.y;
  const int h = blockIdx.x * 256 + threadIdx.x;
  float s = 0.f;
  #pragma unroll
  for (int i = 0; i < 16; ++i) s += part[((size_t)b * 16 + i) * HDIM + h];
  relay[b * HDIM + h] = s * (1.0f / 1024.0f);
}

// h(bf16) = LN(pre(b16) + res(f32)) * g + b
__global__ __launch_bounds__(256) void ln_resid_k(
    const u16* __restrict__ pre, const float* __restrict__ res,
    const float* __restrict__ g, const float* __restrict__ bb,
    u16* __restrict__ out) {
  __shared__ float red[4];
  const int r = blockIdx.x;
  const int tid = threadIdx.x;
  const size_t base = (size_t)r * HDIM;
  float v0 = b2f(pre[base + tid])       + res[base + tid];
  float v1 = b2f(pre[base + tid + 256]) + res[base + tid + 256];
  float v2 = b2f(pre[base + tid + 512]) + res[base + tid + 512];
  const float mu = blk_sum(v0 + v1 + v2, red) * (1.0f / 768.0f);
  v0 -= mu; v1 -= mu; v2 -= mu;
  const float var = blk_sum(v0 * v0 + v1 * v1 + v2 * v2, red) * (1.0f / 768.0f);
  const float rs = rsqrtf(var + 1e-5f);
  out[base + tid]       = f2b(v0 * rs * g[tid]       + bb[tid]);
  out[base + tid + 256] = f2b(v1 * rs * g[tid + 256] + bb[tid + 256]);
  out[base + tid + 512] = f2b(v2 * rs * g[tid + 512] + bb[tid + 512]);
}

// nodes = mask ? 0 : leaky(LN(pre)*g + b)  -> fp32 + bf16 shadow
__global__ __launch_bounds__(256) void ln_leaky_mask_k(
    const u16* __restrict__ pre, const float* __restrict__ g,
    const float* __restrict__ bb, const int* __restrict__ src,
    float* __restrict__ out, u16* __restrict__ outb) {
  __shared__ float red[4];
  const int r = blockIdx.x;
  const int tid = threadIdx.x;
  const size_t base = (size_t)r * HDIM;
  float v0 = b2f(pre[base + tid]);
  float v1 = b2f(pre[base + tid + 256]);
  float v2 = b2f(pre[base + tid + 512]);
  const float mu = blk_sum(v0 + v1 + v2, red) * (1.0f / 768.0f);
  v0 -= mu; v1 -= mu; v2 -= mu;
  const float var = blk_sum(v0 * v0 + v1 * v1 + v2 * v2, red) * (1.0f / 768.0f);
  const float rs = rsqrtf(var + 1e-5f);
  const bool masked = (src[r * 3] == 0);
  float y0 = v0 * rs * g[tid]       + bb[tid];
  float y1 = v1 * rs * g[tid + 256] + bb[tid + 256];
  float y2 = v2 * rs * g[tid + 512] + bb[tid + 512];
  y0 = y0 > 0.f ? y0 : 0.01f * y0;
  y1 = y1 > 0.f ? y1 : 0.01f * y1;
  y2 = y2 > 0.f ? y2 : 0.01f * y2;
  if (masked) { y0 = 0.f; y1 = 0.f; y2 = 0.f; }
  out[base + tid]       = y0;  outb[base + tid]       = f2b(y0);
  out[base + tid + 256] = y1;  outb[base + tid + 256] = f2b(y1);
  out[base + tid + 512] = y2;  outb[base + tid + 512] = f2b(y2);
}

// Ring attention: per (b,l), 4 keys {l-1, l, l+1, relay}.
__global__ __launch_bounds__(256) void ring_attn_k(
    const u16* __restrict__ q, const u16* __restrict__ k,
    const u16* __restrict__ v, const float* __restrict__ rk,
    const float* __restrict__ rv, u16* __restrict__ att) {
  __shared__ float qs[HDIM];
  __shared__ float aw[NHEAD][4];
  const int r = blockIdx.x;
  const int b = r >> 10, l = r & (SEQ - 1);
  const int tid = threadIdx.x;
  const size_t base = (size_t)r * HDIM;
  #pragma unroll
  for (int it = 0; it < 3; ++it) {
    const int idx = tid + it * 256;
    qs[idx] = b2f(q[base + idx]);
  }
  __syncthreads();
  if (tid < NHEAD * 4) {
    const int n = tid >> 2, w = tid & 3;
    float a = 0.f;
    if (w < 3) {
      const int ll = l - 1 + w;
      if (ll >= 0 && ll < SEQ) {
        const u16* kp = k + base + (size_t)(w - 1) * HDIM + n * HD;
        #pragma unroll
        for (int d = 0; d < HD; ++d) a += qs[n * HD + d] * b2f(kp[d]);
      }
    } else {
      const float* kp = rk + b * HDIM + n * HD;
      #pragma unroll
      for (int d = 0; d < HD; ++d) a += qs[n * HD + d] * kp[d];
    }
    aw[n][w] = a * ATT_SCALE;
  }
  __syncthreads();
  if (tid < NHEAD) {
    const float s0 = aw[tid][0], s1 = aw[tid][1], s2 = aw[tid][2], s3 = aw[tid][3];
    const float m = fmaxf(fmaxf(s0, s1), fmaxf(s2, s3));
    const float e0 = __expf(s0 - m), e1 = __expf(s1 - m);
    const float e2 = __expf(s2 - m), e3 = __expf(s3 - m);
    const float inv = 1.0f / (e0 + e1 + e2 + e3);
    aw[tid][0] = e0 * inv; aw[tid][1] = e1 * inv;
    aw[tid][2] = e2 * inv; aw[tid][3] = e3 * inv;
  }
  __syncthreads();
  #pragma unroll
  for (int it = 0; it < 3; ++it) {
    const int idx = tid + it * 256;
    const int n = idx >> 6;
    float acc = aw[n][3] * rv[b * HDIM + idx];
    if (l > 0)       acc += aw[n][0] * b2f(v[base - HDIM + idx]);
    acc += aw[n][1] * b2f(v[base + idx]);
    if (l < SEQ - 1) acc += aw[n][2] * b2f(v[base + HDIM + idx]);
    att[base + idx] = f2b(acc);
  }
}

// Star (relay) attention: per (b,head) block; 1025 keys = [relay; nodes].
__global__ __launch_bounds__(256) void msa2_attn_k(
    const float* __restrict__ q2, const float* __restrict__ rk2,
    const float* __restrict__ rv2, const u16* __restrict__ k2,
    const u16* __restrict__ v2, const int* __restrict__ src,
    float* __restrict__ att) {
  __shared__ float qs[HD];
  __shared__ float sc[SEQ + 1];
  __shared__ float red[4];
  const int bid = blockIdx.x;
  const int b = bid / NHEAD, n = bid % NHEAD;
  const int tid = threadIdx.x;
  const int hb = b * HDIM + n * HD;
  if (tid < HD) qs[tid] = q2[hb + tid];
  __syncthreads();
  float lmax = -1e30f;
  for (int s = tid; s <= SEQ; s += 256) {
    float sco;
    if (s == 0) {
      float a = 0.f;
      #pragma unroll
      for (int d = 0; d < HD; ++d) a += qs[d] * rk2[hb + d];
      sco = a * ATT_SCALE;
    } else {
      const int l = s - 1;
      if (src[(b * SEQ + l) * 3] == 0) {
        sco = -1e30f;
      } else {
        const u16* kp = k2 + ((size_t)b * SEQ + l) * HDIM + n * HD;
        float a = 0.f;
        #pragma unroll
        for (int d = 0; d < HD; ++d) a += qs[d] * b2f(kp[d]);
        sco = a * ATT_SCALE;
      }
    }
    sc[s] = sco;
    lmax = fmaxf(lmax, sco);
  }
  lmax = blk_max(lmax, red);
  float lsum = 0.f;
  for (int s = tid; s <= SEQ; s += 256) {
    const float e = __expf(sc[s] - lmax);
    sc[s] = e;
    lsum += e;
  }
  lsum = blk_sum(lsum, red);
  if (tid < HD) {
    const float inv = 1.0f / lsum;
    float acc = sc[0] * rv2[hb + tid];
    const u16* vp = v2 + (size_t)b * SEQ * HDIM + n * HD + tid;
    for (int l = 0; l < SEQ; ++l) acc += sc[l + 1] * b2f(vp[(size_t)l * HDIM]);
    att[hb + tid] = acc * inv;
  }
}

// Tiny NT projections from 8-row relay activations; one wave per output.
// act: 0=none, 2=leaky(0.01). W/bias fp32 originals.
__global__ __launch_bounds__(256) void relay_proj_k(
    const float* __restrict__ A, int K, int N, int nm,
    const float* W0, const float* W1, const float* W2,
    const float* b0, const float* b1, const float* b2v,
    float* O0, float* O1, float* O2, int act) {
  const int wid = blockIdx.x * 4 + (threadIdx.x >> 6);
  const int lane = threadIdx.x & 63;
  if (wid >= nm * NB * N) return;
  const int mat = wid / (NB * N);
  const int rem = wid % (NB * N);
  const int b = rem / N, n = rem % N;
  const float* W  = mat == 0 ? W0 : (mat == 1 ? W1 : W2);
  const float* bb = mat == 0 ? b0 : (mat == 1 ? b1 : b2v);
  float* O        = mat == 0 ? O0 : (mat == 1 ? O1 : O2);
  const float* a = A + (size_t)b * K;
  const float* wr = W + (size_t)n * K;
  float acc = 0.f;
  for (int k = lane; k < K; k += 64) acc += a[k] * wr[k];
  #pragma unroll
  for (int off = 32; off > 0; off >>= 1) acc += __shfl_down(acc, off, 64);
  if (lane == 0) {
    float v = acc + bb[n];
    if (act == 2) v = v > 0.f ? v : 0.01f * v;
    O[(size_t)b * N + n] = v;
  }
}

// ft[b] = [relay[b] ; nodes[b, positions[b]]]
__global__ __launch_bounds__(256) void ft_k(
    const float* __restrict__ relay, const float* __restrict__ nodes,
    const int* __restrict__ positions, float* __restrict__ ft) {
  const int gid = blockIdx.x * 256 + threadIdx.x;
  const int b = gid / 1536, j = gid % 1536;
  if (j < HDIM) {
    ft[gid] = relay[b * HDIM + j];
  } else {
    const int p = positions[b];
    ft[gid] = nodes[((size_t)b * SEQ + p) * HDIM + (j - HDIM)];
  }
}

// hid[j,b,o] = relu(ft[b] . head_w1[j,o] + head_b1[j,o]); one wave per output
__global__ __launch_bounds__(256) void head1_k(
    const float* __restrict__ ft, const float* __restrict__ w,
    const float* __restrict__ bias, float* __restrict__ hid) {
  const int wid = blockIdx.x * 4 + (threadIdx.x >> 6);
  const int lane = threadIdx.x & 63;
  const int j = wid >> 13;
  const int rem = wid & 8191;
  const int b = rem >> 10, o = rem & 1023;
  const float* a = ft + b * 1536;
  const float* wr = w + ((size_t)j * NHID + o) * 1536;
  float acc = 0.f;
  for (int k = lane; k < 1536; k += 64) acc += a[k] * wr[k];
  #pragma unroll
  for (int off = 32; off > 0; off >>= 1) acc += __shfl_down(acc, off, 64);
  if (lane == 0)
    hid[((size_t)j * NB + b) * NHID + o] = fmaxf(acc + bias[j * NHID + o], 0.f);
}

// out[(b*3+j), o] = hid[j,b] . head_w2[j,o] + head_b2[j,o]  (fp32 out)
__global__ __launch_bounds__(256) void head2_k(
    const float* __restrict__ hid, const float* __restrict__ w,
    const float* __restrict__ bias, float* __restrict__ out) {
  const int wid = blockIdx.x * 4 + (threadIdx.x >> 6);
  const int lane = threadIdx.x & 63;
  const int j = wid / 40000;
  const int rem = wid % 40000;
  const int b = rem / 5000, o = rem % 5000;
  const float* a = hid + ((size_t)j * NB + b) * NHID;
  const float* wr = w + ((size_t)j * NOUT + o) * NHID;
  float acc = 0.f;
  for (int k = lane; k < NHID; k += 64) acc += a[k] * wr[k];
  #pragma unroll
  for (int off = 32; off > 0; off >>= 1) acc += __shfl_down(acc, off, 64);
  if (lane == 0)
    out[(size_t)(b * 3 + j) * NOUT + o] = acc + bias[j * NOUT + o];
}

// ---------------------------------------------------------------------------
extern "C" void kernel_launch(void* const* d_in, const int* in_sizes, int n_in,
                              void* d_out, int out_size, void* d_ws, size_t ws_size,
                              hipStream_t stream) {
  (void)in_sizes; (void)n_in; (void)out_size; (void)ws_size;
  const int* src       = (const int*)d_in[0];
  const int* positions = (const int*)d_in[1];
  const float* emb   = (const float*)d_in[2];
  const float* pt    = (const float*)d_in[3];
  const float* norm_g = (const float*)d_in[4]; const float* norm_b = (const float*)d_in[5];
  const float* pw_w1 = (const float*)d_in[6];  const float* pw_b1 = (const float*)d_in[7];
  const float* pw_w2 = (const float*)d_in[8];  const float* pw_b2 = (const float*)d_in[9];
  const float* pw_g  = (const float*)d_in[10]; const float* pw_bn = (const float*)d_in[11];
  const float* ring_wq = (const float*)d_in[12]; const float* ring_bq = (const float*)d_in[13];
  const float* ring_wk = (const float*)d_in[14]; const float* ring_bk = (const float*)d_in[15];
  const float* ring_wv = (const float*)d_in[16]; const float* ring_bv = (const float*)d_in[17];
  const float* ring_wo = (const float*)d_in[18]; const float* ring_bo = (const float*)d_in[19];
  const float* star_wq = (const float*)d_in[20]; const float* star_bq = (const float*)d_in[21];
  const float* star_wk = (const float*)d_in[22]; const float* star_bk = (const float*)d_in[23];
  const float* star_wv = (const float*)d_in[24]; const float* star_bv = (const float*)d_in[25];
  const float* star_wo = (const float*)d_in[26]; const float* star_bo = (const float*)d_in[27];
  const float* head_w1 = (const float*)d_in[28]; const float* head_b1 = (const float*)d_in[29];
  const float* head_w2 = (const float*)d_in[30]; const float* head_b2 = (const float*)d_in[31];

  // workspace layout
  char* ws = (char*)d_ws;
  const size_t NTOK = (size_t)NB * SEQ * HDIM;            // 6,291,456 elems
  float* nodes   = (float*)(ws);                          // 25,165,824 B
  u16* preln     = (u16*)(ws + NTOK * 4);                 // 12,582,912 B
  u16* cbase     = (u16*)(ws + NTOK * 6);                 // 50,331,648 B (4 slots)
  u16* inner  = cbase;
  u16* slotC0 = cbase;
  u16* slotC1 = cbase + 1 * NTOK;
  u16* slotC2 = cbase + 2 * NTOK;
  u16* slotC3 = cbase + 3 * NTOK;
  u16* shared12  = (u16*)(ws + NTOK * 14);                // 12,582,912 B (h / nodes_b16)
  u16* wc        = (u16*)(ws + NTOK * 16);                // 9,437,184 B weight-cvt
  char* small    = ws + NTOK * 16 + 9437184;
  float* part  = (float*)(small);                          // 393,216
  float* relay = (float*)(small + 393216);
  float* sb0 = (float*)(small + 393216 + 1 * 24576);
  float* sb1 = (float*)(small + 393216 + 2 * 24576);
  float* sb2 = (float*)(small + 393216 + 3 * 24576);
  float* sb3 = (float*)(small + 393216 + 4 * 24576);
  float* ftb = (float*)(small + 393216 + 5 * 24576);
  float* hid = (float*)(small + 393216 + 5 * 24576 + 49152);

  u16* nodes_b16 = shared12;  // alive ln_leaky(i) -> gemm1(i+1) / star(i)
  u16* hbuf      = shared12;  // alive ln_resid(i) -> qkv gemms(i)

  embed_k<<<NB * SEQ, 256, 0, stream>>>(src, emb, pt, nodes, nodes_b16);
  relay_mean1_k<<<dim3(3, 16, NB), 256, 0, stream>>>(nodes, part);
  relay_mean2_k<<<dim3(3, NB), 256, 0, stream>>>(part, relay);

  const int NW1 = DINNER * HDIM;   // 2,359,296 elems per layer slice
  const int NQK = HDIM * HDIM;     // 589,824

  for (int i = 0; i < 2; ++i) {
    const float* pw_w1_l = pw_w1 + (size_t)i * NW1;
    const float* pw_w2_l = pw_w2 + (size_t)i * NW1;
    const float* pw_b1_l = pw_b1 + (size_t)i * DINNER;
    const float* pw_b2_l = pw_b2 + (size_t)i * HDIM;
    const float* pw_g_l  = pw_g + (size_t)i * HDIM;
    const float* pw_bn_l = pw_bn + (size_t)i * HDIM;
    const float* ng_l = norm_g + (size_t)i * HDIM;
    const float* nb_l = norm_b + (size_t)i * HDIM;
    const float* rwq = ring_wq + (size_t)i * NQK; const float* rbq = ring_bq + (size_t)i * HDIM;
    const float* rwk = ring_wk + (size_t)i * NQK; const float* rbk = ring_bk + (size_t)i * HDIM;
    const float* rwv = ring_wv + (size_t)i * NQK; const float* rbv = ring_bv + (size_t)i * HDIM;
    const float* rwo = ring_wo + (size_t)i * NQK; const float* rbo = ring_bo + (size_t)i * HDIM;
    const float* swq = star_wq + (size_t)i * NQK; const float* sbq = star_bq + (size_t)i * HDIM;
    const float* swk = star_wk + (size_t)i * NQK; const float* sbk = star_bk + (size_t)i * HDIM;
    const float* swv = star_wv + (size_t)i * NQK; const float* sbv = star_bv + (size_t)i * HDIM;
    const float* swo = star_wo + (size_t)i * NQK; const float* sbo = star_bo + (size_t)i * HDIM;

    // phase A: convert pw_w1, pw_w2
    u16* wc_pw1 = wc;
    u16* wc_pw2 = wc + NW1;
    {
      Cvt4 a = { pw_w1_l, pw_w2_l, pw_w1_l, pw_w1_l,
                 wc_pw1, wc_pw2, wc_pw1, wc_pw1,
                 NW1 / 4, NW1 / 2, NW1 / 2, NW1 / 2 };
      cvt4_k<<<(NW1 / 2 + 255) / 256, 256, 0, stream>>>(a);
    }
    gemm_bt<1><<<dim3(DINNER / 128, 64, 1), 256, 0, stream>>>(
        nodes_b16, wc_pw1, wc_pw1, wc_pw1, pw_b1_l, pw_b1_l, pw_b1_l,
        inner, inner, inner, NB * SEQ, DINNER, HDIM);
    gemm_bt<0><<<dim3(HDIM / 128, 64, 1), 256, 0, stream>>>(
        inner, wc_pw2, wc_pw2, wc_pw2, pw_b2_l, pw_b2_l, pw_b2_l,
        preln, preln, preln, NB * SEQ, HDIM, DINNER);
    ln_resid_k<<<NB * SEQ, 256, 0, stream>>>(preln, nodes, pw_g_l, pw_bn_l, hbuf);

    // phase B: convert ring wq,wk,wv,wo
    u16* wc_rq = wc;
    u16* wc_rk = wc + NQK;
    u16* wc_rv = wc + 2 * NQK;
    u16* wc_ro = wc + 3 * NQK;
    {
      Cvt4 a = { rwq, rwk, rwv, rwo, wc_rq, wc_rk, wc_rv, wc_ro,
                 NQK / 4, NQK / 2, 3 * NQK / 4, NQK };
      cvt4_k<<<(NQK + 255) / 256, 256, 0, stream>>>(a);
    }
    gemm_bt<0><<<dim3(HDIM / 128, 64, 3), 256, 0, stream>>>(
        hbuf, wc_rq, wc_rk, wc_rv, rbq, rbk, rbv,
        slotC0, slotC1, slotC2, NB * SEQ, HDIM, HDIM);
    relay_proj_k<<<(2 * NB * HDIM) / 4, 256, 0, stream>>>(
        relay, HDIM, HDIM, 2, rwk, rwv, rwk, rbk, rbv, rbk, sb0, sb1, sb2, 0);
    ring_attn_k<<<NB * SEQ, 256, 0, stream>>>(slotC0, slotC1, slotC2, sb0, sb1, slotC3);
    gemm_bt<0><<<dim3(HDIM / 128, 64, 1), 256, 0, stream>>>(
        slotC3, wc_ro, wc_ro, wc_ro, rbo, rbo, rbo,
        preln, preln, preln, NB * SEQ, HDIM, HDIM);
    ln_leaky_mask_k<<<NB * SEQ, 256, 0, stream>>>(preln, ng_l, nb_l, src, nodes, nodes_b16);

    // phase C: convert star wk, wv
    u16* wc_sk = wc;
    u16* wc_sv = wc + NQK;
    {
      Cvt4 a = { swk, swv, swk, swk, wc_sk, wc_sv, wc_sk, wc_sk,
                 NQK / 4, NQK / 2, NQK / 2, NQK / 2 };
      cvt4_k<<<(NQK / 2 + 255) / 256, 256, 0, stream>>>(a);
    }
    gemm_bt<0><<<dim3(HDIM / 128, 64, 2), 256, 0, stream>>>(
        nodes_b16, wc_sk, wc_sv, wc_sv, sbk, sbv, sbv,
        slotC0, slotC1, slotC1, NB * SEQ, HDIM, HDIM);
    relay_proj_k<<<(3 * NB * HDIM) / 4, 256, 0, stream>>>(
        relay, HDIM, HDIM, 3, swq, swk, swv, sbq, sbk, sbv, sb0, sb1, sb2, 0);
    msa2_attn_k<<<NB * NHEAD, 256, 0, stream>>>(sb0, sb1, sb2, slotC0, slotC1, src, sb3);
    relay_proj_k<<<(NB * HDIM) / 4, 256, 0, stream>>>(
        sb3, HDIM, HDIM, 1, swo, swo, swo, sbo, sbo, sbo, relay, sb1, sb2, 2);
  }

  ft_k<<<48, 256, 0, stream>>>(relay, nodes, positions, ftb);
  head1_k<<<(3 * NB * NHID) / 4, 256, 0, stream>>>(ftb, head_w1, head_b1, hid);
  head2_k<<<(3 * NB * NOUT) / 4, 256, 0, stream>>>(hid, head_w2, head_b2, (float*)d_out);
}

// Round 6
// 1038.478 us; speedup vs baseline: 1.5547x; 1.1228x over previous
//
#include <hip/hip_runtime.h>
#include <cstdint>
#include <cstddef>

// ---------------------------------------------------------------------------
// Star-Transformer forward on MI355X. Inputs fp32, output fp32. GEMMs bf16
// MFMA (weights converted per layer into rotating ws buffer), staging via
// global_load_lds width 16. R6: head/proj kernels restructured to one wave
// per WEIGHT ROW (8-batch accumulate) -> single-pass weight streaming.
// ---------------------------------------------------------------------------

typedef unsigned short u16;
typedef __attribute__((ext_vector_type(4))) float f32x4;
typedef __attribute__((ext_vector_type(8))) __bf16 bf16x8;

#define NB 8
#define SEQ 1024
#define HDIM 768
#define NHEAD 12
#define HD 64
#define DINNER 3072
#define NHID 1024
#define NOUT 5000
#define ATT_SCALE 0.125f

static __device__ __forceinline__ float b2f(u16 u) {
  union { float f; uint32_t i; } v; v.i = ((uint32_t)u) << 16; return v.f;
}
static __device__ __forceinline__ u16 f2b(float f) {
  union { float f; uint32_t i; } v; v.f = f;
  uint32_t r = v.i + 0x7fffu + ((v.i >> 16) & 1u);
  return (u16)(r >> 16);
}

// async global->LDS, 16B per lane; LDS dest = wave-uniform base + lane*16.
static __device__ __forceinline__ void gl2lds16(const void* g, void* l) {
  __builtin_amdgcn_global_load_lds(
      (__attribute__((address_space(1))) void*)(uintptr_t)g,
      (__attribute__((address_space(3))) void*)l, 16, 0, 0);
}

static __device__ __forceinline__ float blk_sum(float v, float* red) {
  #pragma unroll
  for (int off = 32; off > 0; off >>= 1) v += __shfl_down(v, off, 64);
  if ((threadIdx.x & 63) == 0) red[threadIdx.x >> 6] = v;
  __syncthreads();
  float r = red[0] + red[1] + red[2] + red[3];
  __syncthreads();
  return r;
}
static __device__ __forceinline__ float blk_max(float v, float* red) {
  #pragma unroll
  for (int off = 32; off > 0; off >>= 1) v = fmaxf(v, __shfl_down(v, off, 64));
  if ((threadIdx.x & 63) == 0) red[threadIdx.x >> 6] = v;
  __syncthreads();
  float r = fmaxf(fmaxf(red[0], red[1]), fmaxf(red[2], red[3]));
  __syncthreads();
  return r;
}

// ---------------------------------------------------------------------------
// Segmented fp32 -> bf16 converter (up to 4 tensors per dispatch).
// ---------------------------------------------------------------------------
struct Cvt4 {
  const float* s0; const float* s1; const float* s2; const float* s3;
  u16* d0; u16* d1; u16* d2; u16* d3;
  int c1, c2, c3, c4;
};
__global__ __launch_bounds__(256) void cvt4_k(Cvt4 a) {
  const int i = blockIdx.x * 256 + threadIdx.x;
  if (i >= a.c4) return;
  const float* s; u16* d; int j;
  if (i < a.c1)      { s = a.s0; d = a.d0; j = i; }
  else if (i < a.c2) { s = a.s1; d = a.d1; j = i - a.c1; }
  else if (i < a.c3) { s = a.s2; d = a.d2; j = i - a.c2; }
  else               { s = a.s3; d = a.d3; j = i - a.c3; }
  const float4 v = ((const float4*)s)[j];
  ushort4 o;
  o.x = f2b(v.x); o.y = f2b(v.y); o.z = f2b(v.z); o.w = f2b(v.w);
  ((ushort4*)d)[j] = o;
}

// ---------------------------------------------------------------------------
// NT GEMM: C[M,N] = act(A[M,K] . Wz[N,K]^T + biasz[N]) for z = blockIdx.z.
// All bf16 operands, fp32 bias, bf16 out. 128x128 tile, 4 waves, 64x64/wave,
// mfma_f32_16x16x32_bf16, global_load_lds width-16 staging. ACT: 0=none 1=relu.
// ---------------------------------------------------------------------------
template <int ACT>
__global__ __launch_bounds__(256) void gemm_bt(
    const u16* __restrict__ A,
    const u16* W0, const u16* W1, const u16* W2,
    const float* b0, const float* b1, const float* b2,
    u16* C0, u16* C1, u16* C2,
    int M, int N, int K) {
  __shared__ u16 As[128 * 32];
  __shared__ u16 Bs[128 * 32];
  const int z = blockIdx.z;
  const u16* W = z == 0 ? W0 : (z == 1 ? W1 : W2);
  const float* bias = z == 0 ? b0 : (z == 1 ? b1 : b2);
  u16* C = z == 0 ? C0 : (z == 1 ? C1 : C2);

  const int tid  = threadIdx.x;
  const int wave = tid >> 6;
  const int lane = tid & 63;
  const int bm = blockIdx.y * 128;
  const int bn = blockIdx.x * 128;
  const int wrq = wave >> 1, wcq = wave & 1;
  const int r16 = lane & 15, quad = lane >> 4;
  const int srow = lane >> 2;        // 0..15
  const int scol = (lane & 3) << 3;  // 0,8,16,24 bf16 elements

  f32x4 acc[4][4] = {};

  for (int k0 = 0; k0 < K; k0 += 32) {
    __syncthreads();
    #pragma unroll
    for (int t = 0; t < 2; ++t) {
      const int rowa = wave * 32 + t * 16;
      gl2lds16(A + (size_t)(bm + rowa + srow) * K + (k0 + scol), (char*)As + (rowa << 6));
      gl2lds16(W + (size_t)(bn + rowa + srow) * K + (k0 + scol), (char*)Bs + (rowa << 6));
    }
    __syncthreads();
    bf16x8 af[4], bf[4];
    #pragma unroll
    for (int i = 0; i < 4; ++i)
      af[i] = *reinterpret_cast<const bf16x8*>(&As[(wrq * 64 + i * 16 + r16) * 32 + quad * 8]);
    #pragma unroll
    for (int j = 0; j < 4; ++j)
      bf[j] = *reinterpret_cast<const bf16x8*>(&Bs[(wcq * 64 + j * 16 + r16) * 32 + quad * 8]);
    #pragma unroll
    for (int i = 0; i < 4; ++i)
      #pragma unroll
      for (int j = 0; j < 4; ++j)
        acc[i][j] = __builtin_amdgcn_mfma_f32_16x16x32_bf16(af[i], bf[j], acc[i][j], 0, 0, 0);
  }

  #pragma unroll
  for (int j = 0; j < 4; ++j) {
    const int n = bn + wcq * 64 + j * 16 + r16;
    const float bv = bias[n];
    #pragma unroll
    for (int i = 0; i < 4; ++i) {
      const int m0 = bm + wrq * 64 + i * 16 + quad * 4;
      #pragma unroll
      for (int r = 0; r < 4; ++r) {
        float vv = acc[i][j][r] + bv;
        if (ACT == 1) vv = fmaxf(vv, 0.0f);
        C[(size_t)(m0 + r) * N + n] = f2b(vv);
      }
    }
  }
}

// x[b,l,.] = emb[src] + pos_table  -> fp32 nodes + bf16 shadow
__global__ __launch_bounds__(256) void embed_k(
    const int* __restrict__ src, const float* __restrict__ emb,
    const float* __restrict__ pt, float* __restrict__ x,
    u16* __restrict__ xb) {
  const int r = blockIdx.x;
  const int l = r & (SEQ - 1);
  const int tid = threadIdx.x;
  #pragma unroll
  for (int it = 0; it < 3; ++it) {
    const int idx = tid + it * 256;
    const int c = idx >> 8, d = idx & 255;
    const int tok = src[r * 3 + c];
    const float v = emb[(size_t)tok * 256 + d] + pt[(size_t)l * HDIM + idx];
    x[(size_t)r * HDIM + idx] = v;
    xb[(size_t)r * HDIM + idx] = f2b(v);
  }
}

// two-stage relay mean
__global__ __launch_bounds__(256) void relay_mean1_k(
    const float* __restrict__ x, float* __restrict__ part) {
  const int cg = blockIdx.x, seg = blockIdx.y, b = blockIdx.z;
  const int h = cg * 256 + threadIdx.x;
  float s = 0.f;
  const int l0 = seg * 64;
  for (int l = l0; l < l0 + 64; ++l) s += x[((size_t)b * SEQ + l) * HDIM + h];
  part[((size_t)b * 16 + seg) * HDIM + h] = s;
}
__global__ __launch_bounds__(256) void relay_mean2_k(
    const float* __restrict__ part, float* __restrict__ relay) {
  const int b = blockIdx.y;
  const int h = blockIdx.x * 256 + threadIdx.x;
  float s = 0.f;
  #pragma unroll
  for (int i = 0; i < 16; ++i) s += part[((size_t)b * 16 + i) * HDIM + h];
  relay[b * HDIM + h] = s * (1.0f / 1024.0f);
}

// h(bf16) = LN(pre(b16) + res(f32)) * g + b
__global__ __launch_bounds__(256) void ln_resid_k(
    const u16* __restrict__ pre, const float* __restrict__ res,
    const float* __restrict__ g, const float* __restrict__ bb,
    u16* __restrict__ out) {
  __shared__ float red[4];
  const int r = blockIdx.x;
  const int tid = threadIdx.x;
  const size_t base = (size_t)r * HDIM;
  float v0 = b2f(pre[base + tid])       + res[base + tid];
  float v1 = b2f(pre[base + tid + 256]) + res[base + tid + 256];
  float v2 = b2f(pre[base + tid + 512]) + res[base + tid + 512];
  const float mu = blk_sum(v0 + v1 + v2, red) * (1.0f / 768.0f);
  v0 -= mu; v1 -= mu; v2 -= mu;
  const float var = blk_sum(v0 * v0 + v1 * v1 + v2 * v2, red) * (1.0f / 768.0f);
  const float rs = rsqrtf(var + 1e-5f);
  out[base + tid]       = f2b(v0 * rs * g[tid]       + bb[tid]);
  out[base + tid + 256] = f2b(v1 * rs * g[tid + 256] + bb[tid + 256]);
  out[base + tid + 512] = f2b(v2 * rs * g[tid + 512] + bb[tid + 512]);
}

// nodes = mask ? 0 : leaky(LN(pre)*g + b)  -> fp32 + bf16 shadow
__global__ __launch_bounds__(256) void ln_leaky_mask_k(
    const u16* __restrict__ pre, const float* __restrict__ g,
    const float* __restrict__ bb, const int* __restrict__ src,
    float* __restrict__ out, u16* __restrict__ outb) {
  __shared__ float red[4];
  const int r = blockIdx.x;
  const int tid = threadIdx.x;
  const size_t base = (size_t)r * HDIM;
  float v0 = b2f(pre[base + tid]);
  float v1 = b2f(pre[base + tid + 256]);
  float v2 = b2f(pre[base + tid + 512]);
  const float mu = blk_sum(v0 + v1 + v2, red) * (1.0f / 768.0f);
  v0 -= mu; v1 -= mu; v2 -= mu;
  const float var = blk_sum(v0 * v0 + v1 * v1 + v2 * v2, red) * (1.0f / 768.0f);
  const float rs = rsqrtf(var + 1e-5f);
  const bool masked = (src[r * 3] == 0);
  float y0 = v0 * rs * g[tid]       + bb[tid];
  float y1 = v1 * rs * g[tid + 256] + bb[tid + 256];
  float y2 = v2 * rs * g[tid + 512] + bb[tid + 512];
  y0 = y0 > 0.f ? y0 : 0.01f * y0;
  y1 = y1 > 0.f ? y1 : 0.01f * y1;
  y2 = y2 > 0.f ? y2 : 0.01f * y2;
  if (masked) { y0 = 0.f; y1 = 0.f; y2 = 0.f; }
  out[base + tid]       = y0;  outb[base + tid]       = f2b(y0);
  out[base + tid + 256] = y1;  outb[base + tid + 256] = f2b(y1);
  out[base + tid + 512] = y2;  outb[base + tid + 512] = f2b(y2);
}

// Ring attention: per (b,l), 4 keys {l-1, l, l+1, relay}.
__global__ __launch_bounds__(256) void ring_attn_k(
    const u16* __restrict__ q, const u16* __restrict__ k,
    const u16* __restrict__ v, const float* __restrict__ rk,
    const float* __restrict__ rv, u16* __restrict__ att) {
  __shared__ float qs[HDIM];
  __shared__ float aw[NHEAD][4];
  const int r = blockIdx.x;
  const int b = r >> 10, l = r & (SEQ - 1);
  const int tid = threadIdx.x;
  const size_t base = (size_t)r * HDIM;
  #pragma unroll
  for (int it = 0; it < 3; ++it) {
    const int idx = tid + it * 256;
    qs[idx] = b2f(q[base + idx]);
  }
  __syncthreads();
  if (tid < NHEAD * 4) {
    const int n = tid >> 2, w = tid & 3;
    float a = 0.f;
    if (w < 3) {
      const int ll = l - 1 + w;
      if (ll >= 0 && ll < SEQ) {
        const u16* kp = k + base + (size_t)(w - 1) * HDIM + n * HD;
        #pragma unroll
        for (int d = 0; d < HD; ++d) a += qs[n * HD + d] * b2f(kp[d]);
      }
    } else {
      const float* kp = rk + b * HDIM + n * HD;
      #pragma unroll
      for (int d = 0; d < HD; ++d) a += qs[n * HD + d] * kp[d];
    }
    aw[n][w] = a * ATT_SCALE;
  }
  __syncthreads();
  if (tid < NHEAD) {
    const float s0 = aw[tid][0], s1 = aw[tid][1], s2 = aw[tid][2], s3 = aw[tid][3];
    const float m = fmaxf(fmaxf(s0, s1), fmaxf(s2, s3));
    const float e0 = __expf(s0 - m), e1 = __expf(s1 - m);
    const float e2 = __expf(s2 - m), e3 = __expf(s3 - m);
    const float inv = 1.0f / (e0 + e1 + e2 + e3);
    aw[tid][0] = e0 * inv; aw[tid][1] = e1 * inv;
    aw[tid][2] = e2 * inv; aw[tid][3] = e3 * inv;
  }
  __syncthreads();
  #pragma unroll
  for (int it = 0; it < 3; ++it) {
    const int idx = tid + it * 256;
    const int n = idx >> 6;
    float acc = aw[n][3] * rv[b * HDIM + idx];
    if (l > 0)       acc += aw[n][0] * b2f(v[base - HDIM + idx]);
    acc += aw[n][1] * b2f(v[base + idx]);
    if (l < SEQ - 1) acc += aw[n][2] * b2f(v[base + HDIM + idx]);
    att[base + idx] = f2b(acc);
  }
}

// Star (relay) attention: per (b,head) block; 1025 keys = [relay; nodes].
__global__ __launch_bounds__(256) void msa2_attn_k(
    const float* __restrict__ q2, const float* __restrict__ rk2,
    const float* __restrict__ rv2, const u16* __restrict__ k2,
    const u16* __restrict__ v2, const int* __restrict__ src,
    float* __restrict__ att) {
  __shared__ float qs[HD];
  __shared__ float sc[SEQ + 1];
  __shared__ float red[4];
  const int bid = blockIdx.x;
  const int b = bid / NHEAD, n = bid % NHEAD;
  const int tid = threadIdx.x;
  const int hb = b * HDIM + n * HD;
  if (tid < HD) qs[tid] = q2[hb + tid];
  __syncthreads();
  float lmax = -1e30f;
  for (int s = tid; s <= SEQ; s += 256) {
    float sco;
    if (s == 0) {
      float a = 0.f;
      #pragma unroll
      for (int d = 0; d < HD; ++d) a += qs[d] * rk2[hb + d];
      sco = a * ATT_SCALE;
    } else {
      const int l = s - 1;
      if (src[(b * SEQ + l) * 3] == 0) {
        sco = -1e30f;
      } else {
        const u16* kp = k2 + ((size_t)b * SEQ + l) * HDIM + n * HD;
        float a = 0.f;
        #pragma unroll
        for (int d = 0; d < HD; ++d) a += qs[d] * b2f(kp[d]);
        sco = a * ATT_SCALE;
      }
    }
    sc[s] = sco;
    lmax = fmaxf(lmax, sco);
  }
  lmax = blk_max(lmax, red);
  float lsum = 0.f;
  for (int s = tid; s <= SEQ; s += 256) {
    const float e = __expf(sc[s] - lmax);
    sc[s] = e;
    lsum += e;
  }
  lsum = blk_sum(lsum, red);
  if (tid < HD) {
    const float inv = 1.0f / lsum;
    float acc = sc[0] * rv2[hb + tid];
    const u16* vp = v2 + (size_t)b * SEQ * HDIM + n * HD + tid;
    for (int l = 0; l < SEQ; ++l) acc += sc[l + 1] * b2f(vp[(size_t)l * HDIM]);
    att[hb + tid] = acc * inv;
  }
}

// Relay projections: one wave per (mat, n) WEIGHT ROW; accumulate 8 batches.
// A rows (8 x 768 fp32 = 24 KB) are L1-resident. act: 0=none, 2=leaky.
__global__ __launch_bounds__(256) void relay_proj_k(
    const float* __restrict__ A, int N, int nm,
    const float* W0, const float* W1, const float* W2,
    const float* b0, const float* b1, const float* b2v,
    float* O0, float* O1, float* O2, int act) {
  const int wid = blockIdx.x * 4 + (threadIdx.x >> 6);
  const int lane = threadIdx.x & 63;
  const int mat = wid / N, n = wid % N;
  const float* W  = mat == 0 ? W0 : (mat == 1 ? W1 : W2);
  const float* bb = mat == 0 ? b0 : (mat == 1 ? b1 : b2v);
  float* O        = mat == 0 ? O0 : (mat == 1 ? O1 : O2);
  const float4* wr = (const float4*)(W + (size_t)n * HDIM);
  float acc[NB] = {};
  #pragma unroll
  for (int it = 0; it < 3; ++it) {
    const int k4 = it * 64 + lane;
    const float4 wv = wr[k4];
    #pragma unroll
    for (int b = 0; b < NB; ++b) {
      const float4 av = *(const float4*)&A[b * HDIM + k4 * 4];
      acc[b] += av.x * wv.x + av.y * wv.y + av.z * wv.z + av.w * wv.w;
    }
  }
  #pragma unroll
  for (int b = 0; b < NB; ++b) {
    float a = acc[b];
    #pragma unroll
    for (int off = 32; off > 0; off >>= 1) a += __shfl_down(a, off, 64);
    if (lane == 0) {
      float v = a + bb[n];
      if (act == 2) v = v > 0.f ? v : 0.01f * v;
      O[(size_t)b * N + n] = v;
    }
  }
}

// ft[b] = [relay[b] ; nodes[b, positions[b]]]
__global__ __launch_bounds__(256) void ft_k(
    const float* __restrict__ relay, const float* __restrict__ nodes,
    const int* __restrict__ positions, float* __restrict__ ft) {
  const int gid = blockIdx.x * 256 + threadIdx.x;
  const int b = gid / 1536, j = gid % 1536;
  if (j < HDIM) {
    ft[gid] = relay[b * HDIM + j];
  } else {
    const int p = positions[b];
    ft[gid] = nodes[((size_t)b * SEQ + p) * HDIM + (j - HDIM)];
  }
}

// head1: one wave per (j,o) weight row; ft (8x1536 = 48 KB) in LDS;
// 8-batch accumulate. grid (NHID/4, 3).
__global__ __launch_bounds__(256) void head1_k(
    const float* __restrict__ ft, const float* __restrict__ w,
    const float* __restrict__ bias, float* __restrict__ hid) {
  __shared__ float fs[NB * 1536];
  const int j = blockIdx.y;
  {
    const float4* s4 = (const float4*)ft;
    float4* d4 = (float4*)fs;
    for (int i = threadIdx.x; i < (NB * 1536) / 4; i += 256) d4[i] = s4[i];
  }
  __syncthreads();
  const int wave = threadIdx.x >> 6, lane = threadIdx.x & 63;
  const int o = blockIdx.x * 4 + wave;
  const float4* wr = (const float4*)(w + ((size_t)j * NHID + o) * 1536);
  float acc[NB] = {};
  #pragma unroll
  for (int it = 0; it < 6; ++it) {
    const int k4 = it * 64 + lane;
    const float4 wv = wr[k4];
    #pragma unroll
    for (int b = 0; b < NB; ++b) {
      const float4 hv = *(const float4*)&fs[b * 1536 + k4 * 4];
      acc[b] += hv.x * wv.x + hv.y * wv.y + hv.z * wv.z + hv.w * wv.w;
    }
  }
  #pragma unroll
  for (int b = 0; b < NB; ++b) {
    float a = acc[b];
    #pragma unroll
    for (int off = 32; off > 0; off >>= 1) a += __shfl_down(a, off, 64);
    if (lane == 0)
      hid[((size_t)j * NB + b) * NHID + o] = fmaxf(a + bias[j * NHID + o], 0.f);
  }
}

// head2: one wave per (j,o) weight row; hid[j] (8x1024 = 32 KB) in LDS;
// 8-batch accumulate. grid (NOUT/4, 3).
__global__ __launch_bounds__(256) void head2_k(
    const float* __restrict__ hid, const float* __restrict__ w,
    const float* __restrict__ bias, float* __restrict__ out) {
  __shared__ float hs[NB * NHID];
  const int j = blockIdx.y;
  {
    const float4* s4 = (const float4*)(hid + (size_t)j * NB * NHID);
    float4* d4 = (float4*)hs;
    for (int i = threadIdx.x; i < (NB * NHID) / 4; i += 256) d4[i] = s4[i];
  }
  __syncthreads();
  const int wave = threadIdx.x >> 6, lane = threadIdx.x & 63;
  const int o = blockIdx.x * 4 + wave;
  const float4* wr = (const float4*)(w + ((size_t)j * NOUT + o) * NHID);
  float acc[NB] = {};
  #pragma unroll
  for (int it = 0; it < 4; ++it) {
    const int k4 = it * 64 + lane;
    const float4 wv = wr[k4];
    #pragma unroll
    for (int b = 0; b < NB; ++b) {
      const float4 hv = *(const float4*)&hs[b * NHID + k4 * 4];
      acc[b] += hv.x * wv.x + hv.y * wv.y + hv.z * wv.z + hv.w * wv.w;
    }
  }
  #pragma unroll
  for (int b = 0; b < NB; ++b) {
    float a = acc[b];
    #pragma unroll
    for (int off = 32; off > 0; off >>= 1) a += __shfl_down(a, off, 64);
    if (lane == 0)
      out[(size_t)(b * 3 + j) * NOUT + o] = a + bias[j * NOUT + o];
  }
}

// ---------------------------------------------------------------------------
extern "C" void kernel_launch(void* const* d_in, const int* in_sizes, int n_in,
                              void* d_out, int out_size, void* d_ws, size_t ws_size,
                              hipStream_t stream) {
  (void)in_sizes; (void)n_in; (void)out_size; (void)ws_size;
  const int* src       = (const int*)d_in[0];
  const int* positions = (const int*)d_in[1];
  const float* emb   = (const float*)d_in[2];
  const float* pt    = (const float*)d_in[3];
  const float* norm_g = (const float*)d_in[4]; const float* norm_b = (const float*)d_in[5];
  const float* pw_w1 = (const float*)d_in[6];  const float* pw_b1 = (const float*)d_in[7];
  const float* pw_w2 = (const float*)d_in[8];  const float* pw_b2 = (const float*)d_in[9];
  const float* pw_g  = (const float*)d_in[10]; const float* pw_bn = (const float*)d_in[11];
  const float* ring_wq = (const float*)d_in[12]; const float* ring_bq = (const float*)d_in[13];
  const float* ring_wk = (const float*)d_in[14]; const float* ring_bk = (const float*)d_in[15];
  const float* ring_wv = (const float*)d_in[16]; const float* ring_bv = (const float*)d_in[17];
  const float* ring_wo = (const float*)d_in[18]; const float* ring_bo = (const float*)d_in[19];
  const float* star_wq = (const float*)d_in[20]; const float* star_bq = (const float*)d_in[21];
  const float* star_wk = (const float*)d_in[22]; const float* star_bk = (const float*)d_in[23];
  const float* star_wv = (const float*)d_in[24]; const float* star_bv = (const float*)d_in[25];
  const float* star_wo = (const float*)d_in[26]; const float* star_bo = (const float*)d_in[27];
  const float* head_w1 = (const float*)d_in[28]; const float* head_b1 = (const float*)d_in[29];
  const float* head_w2 = (const float*)d_in[30]; const float* head_b2 = (const float*)d_in[31];

  // workspace layout
  char* ws = (char*)d_ws;
  const size_t NTOK = (size_t)NB * SEQ * HDIM;            // 6,291,456 elems
  float* nodes   = (float*)(ws);                          // 25,165,824 B
  u16* preln     = (u16*)(ws + NTOK * 4);                 // 12,582,912 B
  u16* cbase     = (u16*)(ws + NTOK * 6);                 // 50,331,648 B (4 slots)
  u16* inner  = cbase;
  u16* slotC0 = cbase;
  u16* slotC1 = cbase + 1 * NTOK;
  u16* slotC2 = cbase + 2 * NTOK;
  u16* slotC3 = cbase + 3 * NTOK;
  u16* shared12  = (u16*)(ws + NTOK * 14);                // 12,582,912 B (h / nodes_b16)
  u16* wc        = (u16*)(ws + NTOK * 16);                // 9,437,184 B weight-cvt
  char* small    = ws + NTOK * 16 + 9437184;
  float* part  = (float*)(small);                          // 393,216
  float* relay = (float*)(small + 393216);
  float* sb0 = (float*)(small + 393216 + 1 * 24576);
  float* sb1 = (float*)(small + 393216 + 2 * 24576);
  float* sb2 = (float*)(small + 393216 + 3 * 24576);
  float* sb3 = (float*)(small + 393216 + 4 * 24576);
  float* ftb = (float*)(small + 393216 + 5 * 24576);
  float* hid = (float*)(small + 393216 + 5 * 24576 + 49152);

  u16* nodes_b16 = shared12;  // alive ln_leaky(i) -> gemm1(i+1) / star(i)
  u16* hbuf      = shared12;  // alive ln_resid(i) -> qkv gemms(i)

  embed_k<<<NB * SEQ, 256, 0, stream>>>(src, emb, pt, nodes, nodes_b16);
  relay_mean1_k<<<dim3(3, 16, NB), 256, 0, stream>>>(nodes, part);
  relay_mean2_k<<<dim3(3, NB), 256, 0, stream>>>(part, relay);

  const int NW1 = DINNER * HDIM;   // 2,359,296 elems per layer slice
  const int NQK = HDIM * HDIM;     // 589,824

  for (int i = 0; i < 2; ++i) {
    const float* pw_w1_l = pw_w1 + (size_t)i * NW1;
    const float* pw_w2_l = pw_w2 + (size_t)i * NW1;
    const float* pw_b1_l = pw_b1 + (size_t)i * DINNER;
    const float* pw_b2_l = pw_b2 + (size_t)i * HDIM;
    const float* pw_g_l  = pw_g + (size_t)i * HDIM;
    const float* pw_bn_l = pw_bn + (size_t)i * HDIM;
    const float* ng_l = norm_g + (size_t)i * HDIM;
    const float* nb_l = norm_b + (size_t)i * HDIM;
    const float* rwq = ring_wq + (size_t)i * NQK; const float* rbq = ring_bq + (size_t)i * HDIM;
    const float* rwk = ring_wk + (size_t)i * NQK; const float* rbk = ring_bk + (size_t)i * HDIM;
    const float* rwv = ring_wv + (size_t)i * NQK; const float* rbv = ring_bv + (size_t)i * HDIM;
    const float* rwo = ring_wo + (size_t)i * NQK; const float* rbo = ring_bo + (size_t)i * HDIM;
    const float* swq = star_wq + (size_t)i * NQK; const float* sbq = star_bq + (size_t)i * HDIM;
    const float* swk = star_wk + (size_t)i * NQK; const float* sbk = star_bk + (size_t)i * HDIM;
    const float* swv = star_wv + (size_t)i * NQK; const float* sbv = star_bv + (size_t)i * HDIM;
    const float* swo = star_wo + (size_t)i * NQK; const float* sbo = star_bo + (size_t)i * HDIM;

    // phase A: convert pw_w1, pw_w2
    u16* wc_pw1 = wc;
    u16* wc_pw2 = wc + NW1;
    {
      Cvt4 a = { pw_w1_l, pw_w2_l, pw_w1_l, pw_w1_l,
                 wc_pw1, wc_pw2, wc_pw1, wc_pw1,
                 NW1 / 4, NW1 / 2, NW1 / 2, NW1 / 2 };
      cvt4_k<<<(NW1 / 2 + 255) / 256, 256, 0, stream>>>(a);
    }
    gemm_bt<1><<<dim3(DINNER / 128, 64, 1), 256, 0, stream>>>(
        nodes_b16, wc_pw1, wc_pw1, wc_pw1, pw_b1_l, pw_b1_l, pw_b1_l,
        inner, inner, inner, NB * SEQ, DINNER, HDIM);
    gemm_bt<0><<<dim3(HDIM / 128, 64, 1), 256, 0, stream>>>(
        inner, wc_pw2, wc_pw2, wc_pw2, pw_b2_l, pw_b2_l, pw_b2_l,
        preln, preln, preln, NB * SEQ, HDIM, DINNER);
    ln_resid_k<<<NB * SEQ, 256, 0, stream>>>(preln, nodes, pw_g_l, pw_bn_l, hbuf);

    // phase B: convert ring wq,wk,wv,wo
    u16* wc_rq = wc;
    u16* wc_rk = wc + NQK;
    u16* wc_rv = wc + 2 * NQK;
    u16* wc_ro = wc + 3 * NQK;
    {
      Cvt4 a = { rwq, rwk, rwv, rwo, wc_rq, wc_rk, wc_rv, wc_ro,
                 NQK / 4, NQK / 2, 3 * NQK / 4, NQK };
      cvt4_k<<<(NQK + 255) / 256, 256, 0, stream>>>(a);
    }
    gemm_bt<0><<<dim3(HDIM / 128, 64, 3), 256, 0, stream>>>(
        hbuf, wc_rq, wc_rk, wc_rv, rbq, rbk, rbv,
        slotC0, slotC1, slotC2, NB * SEQ, HDIM, HDIM);
    relay_proj_k<<<2 * HDIM / 4, 256, 0, stream>>>(
        relay, HDIM, 2, rwk, rwv, rwk, rbk, rbv, rbk, sb0, sb1, sb2, 0);
    ring_attn_k<<<NB * SEQ, 256, 0, stream>>>(slotC0, slotC1, slotC2, sb0, sb1, slotC3);
    gemm_bt<0><<<dim3(HDIM / 128, 64, 1), 256, 0, stream>>>(
        slotC3, wc_ro, wc_ro, wc_ro, rbo, rbo, rbo,
        preln, preln, preln, NB * SEQ, HDIM, HDIM);
    ln_leaky_mask_k<<<NB * SEQ, 256, 0, stream>>>(preln, ng_l, nb_l, src, nodes, nodes_b16);

    // phase C: convert star wk, wv
    u16* wc_sk = wc;
    u16* wc_sv = wc + NQK;
    {
      Cvt4 a = { swk, swv, swk, swk, wc_sk, wc_sv, wc_sk, wc_sk,
                 NQK / 4, NQK / 2, NQK / 2, NQK / 2 };
      cvt4_k<<<(NQK / 2 + 255) / 256, 256, 0, stream>>>(a);
    }
    gemm_bt<0><<<dim3(HDIM / 128, 64, 2), 256, 0, stream>>>(
        nodes_b16, wc_sk, wc_sv, wc_sv, sbk, sbv, sbv,
        slotC0, slotC1, slotC1, NB * SEQ, HDIM, HDIM);
    relay_proj_k<<<3 * HDIM / 4, 256, 0, stream>>>(
        relay, HDIM, 3, swq, swk, swv, sbq, sbk, sbv, sb0, sb1, sb2, 0);
    msa2_attn_k<<<NB * NHEAD, 256, 0, stream>>>(sb0, sb1, sb2, slotC0, slotC1, src, sb3);
    relay_proj_k<<<HDIM / 4, 256, 0, stream>>>(
        sb3, HDIM, 1, swo, swo, swo, sbo, sbo, sbo, relay, sb1, sb2, 2);
  }

  ft_k<<<48, 256, 0, stream>>>(relay, nodes, positions, ftb);
  head1_k<<<dim3(NHID / 4, 3), 256, 0, stream>>>(ftb, head_w1, head_b1, hid);
  head2_k<<<dim3(NOUT / 4, 3), 256, 0, stream>>>(hid, head_w2, head_b2, (float*)d_out);
}